// Round 1
// baseline (942.311 us; speedup 1.0000x reference)
//
#include <hip/hip_runtime.h>

// GCN 2-layer: out = S·relu(S·(x·W1)+b1)·W2 + b2, S = D^-1/2 (A+I) D^-1/2
// Strategy: build CSR-by-dst once (count/scan/fill), then both layers are
// gather-aggregations of 16-wide features (layer2 reassociated: (S·h1)·W2).

__device__ __forceinline__ float fcomp(const float4& v, int i) {
  return i == 0 ? v.x : i == 1 ? v.y : i == 2 ? v.z : v.w;
}

// ---- degree (weighted) + edge count per dst -------------------------------
__global__ __launch_bounds__(256) void k_deg_cnt(
    const int* __restrict__ ei, const float* __restrict__ ew,
    float* __restrict__ deg, int* __restrict__ cnt, int ne) {
  int e = blockIdx.x * 256 + threadIdx.x;
  if (e >= ne) return;
  int d = ei[ne + e];          // edge_index[1][e] = dst
  atomicAdd(&deg[d], ew[e]);
  atomicAdd(&cnt[d], 1);
}

// ---- dinv = 1/sqrt(deg_edges + 1 self-loop) -------------------------------
__global__ __launch_bounds__(256) void k_dinv(
    const float* __restrict__ deg, float* __restrict__ dinv, int n) {
  int i = blockIdx.x * 256 + threadIdx.x;
  if (i < n) dinv[i] = 1.0f / sqrtf(deg[i] + 1.0f);
}

// ---- scan step 1: per-1024-chunk sums -------------------------------------
__global__ __launch_bounds__(256) void k_blocksum(
    const int* __restrict__ cnt, int* __restrict__ bsum, int n) {
  int base = blockIdx.x * 1024;
  int t = threadIdx.x;
  int v = 0;
#pragma unroll
  for (int s = 0; s < 4; ++s) {
    int i = base + t + s * 256;
    if (i < n) v += cnt[i];
  }
#pragma unroll
  for (int off = 32; off > 0; off >>= 1) v += __shfl_down(v, off);
  __shared__ int wsum[4];
  int wid = t >> 6;
  if ((t & 63) == 0) wsum[wid] = v;
  __syncthreads();
  if (t == 0) bsum[blockIdx.x] = wsum[0] + wsum[1] + wsum[2] + wsum[3];
}

// ---- scan step 2: serial exclusive scan of ~98 block sums -----------------
__global__ void k_scanb(int* __restrict__ bsum, int* __restrict__ rs, int nb, int n) {
  if (threadIdx.x == 0 && blockIdx.x == 0) {
    int acc = 0;
    for (int b = 0; b < nb; ++b) { int v = bsum[b]; bsum[b] = acc; acc += v; }
    rs[n] = acc;  // == ne
  }
}

// ---- scan step 3: fine exclusive scan within chunk ------------------------
__global__ __launch_bounds__(256) void k_scan_fine(
    const int* __restrict__ cnt, const int* __restrict__ bsum,
    int* __restrict__ rs, int n) {
  int base = blockIdx.x * 1024;
  int t = threadIdx.x;
  int i0 = base + t * 4;
  int v[4];
#pragma unroll
  for (int s = 0; s < 4; ++s) { int i = i0 + s; v[s] = (i < n) ? cnt[i] : 0; }
  int tsum = v[0] + v[1] + v[2] + v[3];
  int incl = tsum;
#pragma unroll
  for (int off = 1; off < 64; off <<= 1) {
    int u = __shfl_up(incl, off);
    if ((t & 63) >= off) incl += u;
  }
  __shared__ int wtot[4];
  int wid = t >> 6;
  if ((t & 63) == 63) wtot[wid] = incl;
  __syncthreads();
  int woff = 0;
#pragma unroll
  for (int w = 0; w < 3; ++w) if (w < wid) woff += wtot[w];
  int run = bsum[blockIdx.x] + woff + (incl - tsum);
#pragma unroll
  for (int s = 0; s < 4; ++s) {
    int i = i0 + s;
    if (i < n) rs[i] = run;
    run += v[s];
  }
}

// ---- CSR fill: csr[pos] = {src, norm} grouped by dst ----------------------
__global__ __launch_bounds__(256) void k_fill(
    const int* __restrict__ ei, const float* __restrict__ ew,
    const float* __restrict__ dinv, const int* __restrict__ rs,
    int* __restrict__ cursor, int2* __restrict__ csr, int ne) {
  int e = blockIdx.x * 256 + threadIdx.x;
  if (e >= ne) return;
  int s = ei[e];
  int d = ei[ne + e];
  float nrm = dinv[s] * ew[e] * dinv[d];
  int pos = rs[d] + atomicAdd(&cursor[d], 1);
  csr[pos] = make_int2(s, __float_as_int(nrm));
}

// ---- h1pre = x @ W1  (N x 512 @ 512 x 16) ---------------------------------
// 4 threads per row-pair (k-quarters), W1 broadcast from LDS, float4 x loads.
__global__ __launch_bounds__(256) void k_xw1(
    const float* __restrict__ x, const float* __restrict__ W1,
    float* __restrict__ h1pre, int n) {
  __shared__ float W1s[512 * 16];
  {
    const float4* w14 = (const float4*)W1;
    float4* dst4 = (float4*)W1s;
#pragma unroll
    for (int i = 0; i < 8; ++i) dst4[threadIdx.x + i * 256] = w14[threadIdx.x + i * 256];
  }
  __syncthreads();
  int gtid = blockIdx.x * 256 + threadIdx.x;
  int rp = gtid >> 2, q = gtid & 3;
  int r0 = rp * 2;
  if (r0 >= n) return;  // whole waves exit together when n*2 % 128 == 0
  int r1 = r0 + 1;
  bool has1 = (r1 < n);
  const float4* x4 = (const float4*)x;
  const float4* W1s4 = (const float4*)W1s;
  float acc0[16], acc1[16];
#pragma unroll
  for (int j = 0; j < 16; ++j) { acc0[j] = 0.f; acc1[j] = 0.f; }
  int kb = q * 32;  // float4 index base within row (row = 128 float4)
  long rb0 = (long)r0 * 128 + kb;
  long rb1 = (long)r1 * 128 + kb;
  for (int c = 0; c < 32; ++c) {
    float4 a = x4[rb0 + c];
    float4 b = has1 ? x4[rb1 + c] : make_float4(0.f, 0.f, 0.f, 0.f);
    int k = (kb + c) * 4;
#pragma unroll
    for (int i = 0; i < 4; ++i) {
      float ai = fcomp(a, i), bi = fcomp(b, i);
#pragma unroll
      for (int j4 = 0; j4 < 4; ++j4) {
        float4 w = W1s4[(k + i) * 4 + j4];
        acc0[j4 * 4 + 0] = fmaf(ai, w.x, acc0[j4 * 4 + 0]);
        acc0[j4 * 4 + 1] = fmaf(ai, w.y, acc0[j4 * 4 + 1]);
        acc0[j4 * 4 + 2] = fmaf(ai, w.z, acc0[j4 * 4 + 2]);
        acc0[j4 * 4 + 3] = fmaf(ai, w.w, acc0[j4 * 4 + 3]);
        acc1[j4 * 4 + 0] = fmaf(bi, w.x, acc1[j4 * 4 + 0]);
        acc1[j4 * 4 + 1] = fmaf(bi, w.y, acc1[j4 * 4 + 1]);
        acc1[j4 * 4 + 2] = fmaf(bi, w.z, acc1[j4 * 4 + 2]);
        acc1[j4 * 4 + 3] = fmaf(bi, w.w, acc1[j4 * 4 + 3]);
      }
    }
  }
  // reduce across the 4 k-quarter lanes (quads are wave-aligned)
#pragma unroll
  for (int j = 0; j < 16; ++j) {
    acc0[j] += __shfl_xor(acc0[j], 1);
    acc0[j] += __shfl_xor(acc0[j], 2);
    acc1[j] += __shfl_xor(acc1[j], 1);
    acc1[j] += __shfl_xor(acc1[j], 2);
  }
  if (q == 0) {
    float4* o4 = (float4*)h1pre;
#pragma unroll
    for (int j4 = 0; j4 < 4; ++j4) {
      o4[(long)r0 * 4 + j4] =
          make_float4(acc0[4 * j4], acc0[4 * j4 + 1], acc0[4 * j4 + 2], acc0[4 * j4 + 3]);
      if (has1)
        o4[(long)r1 * 4 + j4] =
            make_float4(acc1[4 * j4], acc1[4 * j4 + 1], acc1[4 * j4 + 2], acc1[4 * j4 + 3]);
    }
  }
}

// ---- gather-aggregate: out[i][j] = dinv2[i]*hin[i][j] + sum_e norm*hin[src][j]
// MODE 1: + b1, relu (layer-1 epilogue).  MODE 2: raw (pre-W2).
template <int MODE>
__global__ __launch_bounds__(256) void k_agg(
    const float* __restrict__ hin, const int2* __restrict__ csr,
    const int* __restrict__ rs, const float* __restrict__ dinv,
    const float* __restrict__ bias, float* __restrict__ out, int n) {
  int gtid = blockIdx.x * 256 + threadIdx.x;
  int node = gtid >> 4, j = gtid & 15;
  if (node >= n) return;
  float dv = dinv[node];
  float acc = dv * dv * hin[(long)node * 16 + j];  // self-loop (norm = dinv^2)
  int e = rs[node], e1 = rs[node + 1];
  while (e < e1) {
    int2 en = csr[e];
    ++e;
    acc = fmaf(__int_as_float(en.y), hin[(long)en.x * 16 + j], acc);
  }
  if (MODE == 1)
    out[(long)node * 16 + j] = fmaxf(acc + bias[j], 0.0f);
  else
    out[(long)node * 16 + j] = acc;
}

// ---- out = agg2 @ W2 + b2  (N x 16 @ 16 x 64) -----------------------------
__global__ __launch_bounds__(256) void k_out(
    const float* __restrict__ agg2, const float* __restrict__ W2,
    const float* __restrict__ b2, float* __restrict__ out, int n) {
  __shared__ float W2s[16 * 64];
#pragma unroll
  for (int s = 0; s < 4; ++s) W2s[threadIdx.x + s * 256] = W2[threadIdx.x + s * 256];
  __syncthreads();
  int gtid = blockIdx.x * 256 + threadIdx.x;
  int i = gtid >> 6, o = gtid & 63;
  if (i >= n) return;
  float acc = b2[o];
#pragma unroll
  for (int j = 0; j < 16; ++j)
    acc = fmaf(agg2[(long)i * 16 + j], W2s[j * 64 + o], acc);
  out[(long)i * 64 + o] = acc;
}

extern "C" void kernel_launch(void* const* d_in, const int* in_sizes, int n_in,
                              void* d_out, int out_size, void* d_ws, size_t ws_size,
                              hipStream_t stream) {
  const float* x  = (const float*)d_in[0];
  const int*   ei = (const int*)d_in[1];   // [2, E] int32 (harness narrows int64)
  const float* ew = (const float*)d_in[2];
  const float* W1 = (const float*)d_in[3];
  const float* b1 = (const float*)d_in[4];
  const float* W2 = (const float*)d_in[5];
  const float* b2 = (const float*)d_in[6];
  float* out = (float*)d_out;
  int n  = in_sizes[0] / 512;
  int ne = in_sizes[1] / 2;

  char* ws = (char*)d_ws;
  size_t off = 0;
  auto alloc = [&](size_t bytes) {
    size_t r = off;
    off += (bytes + 255) & ~(size_t)255;
    return r;
  };
  float* deg    = (float*)(ws + alloc((size_t)n * 4));
  int*   cnt    = (int*)  (ws + alloc((size_t)n * 4));
  int*   cursor = (int*)  (ws + alloc((size_t)n * 4));
  size_t zero_span = off;  // [0, zero_span) must be 0 each call
  float* dinv   = (float*)(ws + alloc((size_t)n * 4));
  int*   rs     = (int*)  (ws + alloc((size_t)(n + 1) * 4));
  int*   bsum   = (int*)  (ws + alloc(4096));
  float* h1pre  = (float*)(ws + alloc((size_t)n * 16 * 4));
  float* h1     = (float*)(ws + alloc((size_t)n * 16 * 4));
  float* agg2   = (float*)(ws + alloc((size_t)n * 16 * 4));
  int2*  csr    = (int2*) (ws + alloc((size_t)ne * 8));
  (void)ws_size; (void)n_in; (void)out_size;

  hipMemsetAsync(d_ws, 0, zero_span, stream);

  int gE = (ne + 255) / 256;
  k_deg_cnt<<<gE, 256, 0, stream>>>(ei, ew, deg, cnt, ne);
  k_dinv<<<(n + 255) / 256, 256, 0, stream>>>(deg, dinv, n);

  int nb = (n + 1023) / 1024;
  k_blocksum<<<nb, 256, 0, stream>>>(cnt, bsum, n);
  k_scanb<<<1, 64, 0, stream>>>(bsum, rs, nb, n);
  k_scan_fine<<<nb, 256, 0, stream>>>(cnt, bsum, rs, n);
  k_fill<<<gE, 256, 0, stream>>>(ei, ew, dinv, rs, cursor, csr, ne);

  int nrp = (n + 1) / 2;
  k_xw1<<<(nrp * 4 + 255) / 256, 256, 0, stream>>>(x, W1, h1pre, n);

  int gN16 = (n * 16 + 255) / 256;
  k_agg<1><<<gN16, 256, 0, stream>>>(h1pre, csr, rs, dinv, b1, h1, n);
  k_agg<2><<<gN16, 256, 0, stream>>>(h1, csr, rs, dinv, nullptr, agg2, n);

  k_out<<<(n * 64 + 255) / 256, 256, 0, stream>>>(agg2, W2, b2, out, n);
}

// Round 2
// 653.796 us; speedup vs baseline: 1.4413x; 1.4413x over previous
//
#include <hip/hip_runtime.h>

// GCN 2-layer: out = S·relu(S·(x·W1)+b1)·W2 + b2, S = D^-1/2 (A+I) D^-1/2
// R1 strategy: single-atomic-pass padded CSR (capacity 64/node + overflow
// list), degree via row-sum gather (no float atomics), norm folded into the
// gather-aggregation kernels. Layer2 reassociated: (S·h1)·W2.

constexpr int CAP = 64;          // padded row capacity (Poisson(32) tail ~4e-6)
constexpr int OVF_CAP = 65536;   // overflow edge capacity

__device__ __forceinline__ float fcomp(const float4& v, int i) {
  return i == 0 ? v.x : i == 1 ? v.y : i == 2 ? v.z : v.w;
}

// ---- padded-CSR fill: one int atomic per edge -----------------------------
__global__ __launch_bounds__(256) void k_fill_pad(
    const int* __restrict__ ei, const float* __restrict__ ew,
    int* __restrict__ cnt, int2* __restrict__ csrp,
    int4* __restrict__ ovf, int* __restrict__ ovf_cnt, int ne) {
  int e = blockIdx.x * 256 + threadIdx.x;
  if (e >= ne) return;
  int s = ei[e];
  int d = ei[ne + e];
  float w = ew[e];
  int pos = atomicAdd(&cnt[d], 1);
  if (pos < CAP) {
    csrp[(long)d * CAP + pos] = make_int2(s, __float_as_int(w));
  } else {
    int o = atomicAdd(ovf_cnt, 1);
    if (o < OVF_CAP) ovf[o] = make_int4(d, s, __float_as_int(w), 0);
  }
}

// ---- deg[d] = sum of row weights (8 lanes per node, no atomics) -----------
__global__ __launch_bounds__(256) void k_deg(
    const int2* __restrict__ csrp, const int* __restrict__ cnt,
    float* __restrict__ deg, int n) {
  int gtid = blockIdx.x * 256 + threadIdx.x;
  int node = gtid >> 3, l = gtid & 7;
  if (node >= n) return;
  int kend = min(cnt[node], CAP);
  float v = 0.f;
  for (int k = l; k < kend; k += 8) v += __int_as_float(csrp[(long)node * CAP + k].y);
  v += __shfl_xor(v, 1);
  v += __shfl_xor(v, 2);
  v += __shfl_xor(v, 4);
  if (l == 0) deg[node] = v;
}

__global__ __launch_bounds__(256) void k_ovf_deg(
    const int4* __restrict__ ovf, const int* __restrict__ ovf_cnt,
    float* __restrict__ deg) {
  int m = min(*ovf_cnt, OVF_CAP);
  for (int i = blockIdx.x * 256 + threadIdx.x; i < m; i += gridDim.x * 256)
    atomicAdd(&deg[ovf[i].x], __int_as_float(ovf[i].z));
}

// ---- dinv = 1/sqrt(deg_edges + 1 self-loop) -------------------------------
__global__ __launch_bounds__(256) void k_dinv(
    const float* __restrict__ deg, float* __restrict__ dinv, int n) {
  int i = blockIdx.x * 256 + threadIdx.x;
  if (i < n) dinv[i] = 1.0f / sqrtf(deg[i] + 1.0f);
}

// ---- h1pre = x @ W1  (N x 512 @ 512 x 16) ---------------------------------
__global__ __launch_bounds__(256) void k_xw1(
    const float* __restrict__ x, const float* __restrict__ W1,
    float* __restrict__ h1pre, int n) {
  __shared__ float W1s[512 * 16];
  {
    const float4* w14 = (const float4*)W1;
    float4* dst4 = (float4*)W1s;
#pragma unroll
    for (int i = 0; i < 8; ++i) dst4[threadIdx.x + i * 256] = w14[threadIdx.x + i * 256];
  }
  __syncthreads();
  int gtid = blockIdx.x * 256 + threadIdx.x;
  int rp = gtid >> 2, q = gtid & 3;
  int r0 = rp * 2;
  if (r0 >= n) return;
  int r1 = r0 + 1;
  bool has1 = (r1 < n);
  const float4* x4 = (const float4*)x;
  const float4* W1s4 = (const float4*)W1s;
  float acc0[16], acc1[16];
#pragma unroll
  for (int j = 0; j < 16; ++j) { acc0[j] = 0.f; acc1[j] = 0.f; }
  int kb = q * 32;
  long rb0 = (long)r0 * 128 + kb;
  long rb1 = (long)r1 * 128 + kb;
  for (int c = 0; c < 32; ++c) {
    float4 a = x4[rb0 + c];
    float4 b = has1 ? x4[rb1 + c] : make_float4(0.f, 0.f, 0.f, 0.f);
    int k = (kb + c) * 4;
#pragma unroll
    for (int i = 0; i < 4; ++i) {
      float ai = fcomp(a, i), bi = fcomp(b, i);
#pragma unroll
      for (int j4 = 0; j4 < 4; ++j4) {
        float4 w = W1s4[(k + i) * 4 + j4];
        acc0[j4 * 4 + 0] = fmaf(ai, w.x, acc0[j4 * 4 + 0]);
        acc0[j4 * 4 + 1] = fmaf(ai, w.y, acc0[j4 * 4 + 1]);
        acc0[j4 * 4 + 2] = fmaf(ai, w.z, acc0[j4 * 4 + 2]);
        acc0[j4 * 4 + 3] = fmaf(ai, w.w, acc0[j4 * 4 + 3]);
        acc1[j4 * 4 + 0] = fmaf(bi, w.x, acc1[j4 * 4 + 0]);
        acc1[j4 * 4 + 1] = fmaf(bi, w.y, acc1[j4 * 4 + 1]);
        acc1[j4 * 4 + 2] = fmaf(bi, w.z, acc1[j4 * 4 + 2]);
        acc1[j4 * 4 + 3] = fmaf(bi, w.w, acc1[j4 * 4 + 3]);
      }
    }
  }
#pragma unroll
  for (int j = 0; j < 16; ++j) {
    acc0[j] += __shfl_xor(acc0[j], 1);
    acc0[j] += __shfl_xor(acc0[j], 2);
    acc1[j] += __shfl_xor(acc1[j], 1);
    acc1[j] += __shfl_xor(acc1[j], 2);
  }
  if (q == 0) {
    float4* o4 = (float4*)h1pre;
#pragma unroll
    for (int j4 = 0; j4 < 4; ++j4) {
      o4[(long)r0 * 4 + j4] =
          make_float4(acc0[4 * j4], acc0[4 * j4 + 1], acc0[4 * j4 + 2], acc0[4 * j4 + 3]);
      if (has1)
        o4[(long)r1 * 4 + j4] =
            make_float4(acc1[4 * j4], acc1[4 * j4 + 1], acc1[4 * j4 + 2], acc1[4 * j4 + 3]);
    }
  }
}

// ---- gather-aggregate (raw): out[i][j] = dv*(dv*hin[i][j] + Σ w*dinv[s]*hin[s][j])
__global__ __launch_bounds__(256) void k_agg(
    const float* __restrict__ hin, const int2* __restrict__ csrp,
    const int* __restrict__ cnt, const float* __restrict__ dinv,
    float* __restrict__ out, int n) {
  int gtid = blockIdx.x * 256 + threadIdx.x;
  int node = gtid >> 4, j = gtid & 15;
  if (node >= n) return;
  float dv = dinv[node];
  float acc = dv * hin[(long)node * 16 + j];
  int kend = min(cnt[node], CAP);
  const int2* row = csrp + (long)node * CAP;
  for (int k = 0; k < kend; ++k) {
    int2 en = row[k];
    float f = __int_as_float(en.y) * dinv[en.x];
    acc = fmaf(f, hin[(long)en.x * 16 + j], acc);
  }
  out[(long)node * 16 + j] = dv * acc;
}

// ---- overflow-edge aggregate (rare path, normally 0 edges) ----------------
__global__ __launch_bounds__(256) void k_ovf_agg(
    const int4* __restrict__ ovf, const int* __restrict__ ovf_cnt,
    const float* __restrict__ dinv, const float* __restrict__ hin,
    float* __restrict__ out) {
  int m = min(*ovf_cnt, OVF_CAP);
  for (int t = blockIdx.x * 256 + threadIdx.x; t < m * 16; t += gridDim.x * 256) {
    int i = t >> 4, j = t & 15;
    int4 e = ovf[i];
    float f = dinv[e.x] * dinv[e.y] * __int_as_float(e.z);
    atomicAdd(&out[(long)e.x * 16 + j], f * hin[(long)e.y * 16 + j]);
  }
}

// ---- layer-1 epilogue: bias + relu ----------------------------------------
__global__ __launch_bounds__(256) void k_bias_relu(
    float* __restrict__ h, const float* __restrict__ b, int n) {
  int t = blockIdx.x * 256 + threadIdx.x;
  if (t < n * 16) h[t] = fmaxf(h[t] + b[t & 15], 0.0f);
}

// ---- out = agg2 @ W2 + b2  (N x 16 @ 16 x 64) -----------------------------
__global__ __launch_bounds__(256) void k_out(
    const float* __restrict__ agg2, const float* __restrict__ W2,
    const float* __restrict__ b2, float* __restrict__ out, int n) {
  __shared__ float W2s[16 * 64];
#pragma unroll
  for (int s = 0; s < 4; ++s) W2s[threadIdx.x + s * 256] = W2[threadIdx.x + s * 256];
  __syncthreads();
  int gtid = blockIdx.x * 256 + threadIdx.x;
  int i = gtid >> 6, o = gtid & 63;
  if (i >= n) return;
  float acc = b2[o];
#pragma unroll
  for (int j = 0; j < 16; ++j)
    acc = fmaf(agg2[(long)i * 16 + j], W2s[j * 64 + o], acc);
  out[(long)i * 64 + o] = acc;
}

extern "C" void kernel_launch(void* const* d_in, const int* in_sizes, int n_in,
                              void* d_out, int out_size, void* d_ws, size_t ws_size,
                              hipStream_t stream) {
  const float* x  = (const float*)d_in[0];
  const int*   ei = (const int*)d_in[1];
  const float* ew = (const float*)d_in[2];
  const float* W1 = (const float*)d_in[3];
  const float* b1 = (const float*)d_in[4];
  const float* W2 = (const float*)d_in[5];
  const float* b2 = (const float*)d_in[6];
  float* out = (float*)d_out;
  int n  = in_sizes[0] / 512;
  int ne = in_sizes[1] / 2;

  char* ws = (char*)d_ws;
  size_t off = 0;
  auto alloc = [&](size_t bytes) {
    size_t r = off;
    off += (bytes + 255) & ~(size_t)255;
    return r;
  };
  int*   cnt     = (int*)  (ws + alloc((size_t)n * 4));
  int*   ovf_cnt = (int*)  (ws + alloc(4));
  size_t zero_span = off;                       // [0, zero_span) zeroed per call
  float* deg     = (float*)(ws + alloc((size_t)n * 4));
  float* dinv    = (float*)(ws + alloc((size_t)n * 4));
  float* h1pre   = (float*)(ws + alloc((size_t)n * 16 * 4));
  float* h1      = (float*)(ws + alloc((size_t)n * 16 * 4));
  float* agg2    = (float*)(ws + alloc((size_t)n * 16 * 4));
  int2*  csrp    = (int2*) (ws + alloc((size_t)n * CAP * 8));
  int4*  ovf     = (int4*) (ws + alloc((size_t)OVF_CAP * 16));
  (void)ws_size; (void)n_in; (void)out_size;

  hipMemsetAsync(d_ws, 0, zero_span, stream);

  int gE = (ne + 255) / 256;
  k_fill_pad<<<gE, 256, 0, stream>>>(ei, ew, cnt, csrp, ovf, ovf_cnt, ne);

  k_deg<<<(n * 8 + 255) / 256, 256, 0, stream>>>(csrp, cnt, deg, n);
  k_ovf_deg<<<16, 256, 0, stream>>>(ovf, ovf_cnt, deg);
  k_dinv<<<(n + 255) / 256, 256, 0, stream>>>(deg, dinv, n);

  int nrp = (n + 1) / 2;
  k_xw1<<<(nrp * 4 + 255) / 256, 256, 0, stream>>>(x, W1, h1pre, n);

  int gN16 = (n * 16 + 255) / 256;
  k_agg<<<gN16, 256, 0, stream>>>(h1pre, csrp, cnt, dinv, h1, n);
  k_ovf_agg<<<64, 256, 0, stream>>>(ovf, ovf_cnt, dinv, h1pre, h1);
  k_bias_relu<<<gN16, 256, 0, stream>>>(h1, b1, n);

  k_agg<<<gN16, 256, 0, stream>>>(h1, csrp, cnt, dinv, agg2, n);
  k_ovf_agg<<<64, 256, 0, stream>>>(ovf, ovf_cnt, dinv, h1, agg2);

  k_out<<<(n * 64 + 255) / 256, 256, 0, stream>>>(agg2, W2, b2, out, n);
}

// Round 3
// 472.007 us; speedup vs baseline: 1.9964x; 1.3851x over previous
//
#include <hip/hip_runtime.h>

// GCN 2-layer: out = S·relu(S·(x·W1)+b1)·W2 + b2, S = D^-1/2 (A+I) D^-1/2
// R2: k_xw1 rewritten — float4-interleaved k-quarters (wave reads contiguous
// 64B lines per instruction; no cache-retention dependence) + transposed W1
// in LDS (conflict-free ds_read_b128). Rest unchanged from R1.

constexpr int CAP = 64;          // padded row capacity (Poisson(32) tail ~4e-6)
constexpr int OVF_CAP = 65536;   // overflow edge capacity

// ---- padded-CSR fill: one int atomic per edge -----------------------------
__global__ __launch_bounds__(256) void k_fill_pad(
    const int* __restrict__ ei, const float* __restrict__ ew,
    int* __restrict__ cnt, int2* __restrict__ csrp,
    int4* __restrict__ ovf, int* __restrict__ ovf_cnt, int ne) {
  int e = blockIdx.x * 256 + threadIdx.x;
  if (e >= ne) return;
  int s = ei[e];
  int d = ei[ne + e];
  float w = ew[e];
  int pos = atomicAdd(&cnt[d], 1);
  if (pos < CAP) {
    csrp[(long)d * CAP + pos] = make_int2(s, __float_as_int(w));
  } else {
    int o = atomicAdd(ovf_cnt, 1);
    if (o < OVF_CAP) ovf[o] = make_int4(d, s, __float_as_int(w), 0);
  }
}

// ---- deg[d] = sum of row weights (8 lanes per node, no atomics) -----------
__global__ __launch_bounds__(256) void k_deg(
    const int2* __restrict__ csrp, const int* __restrict__ cnt,
    float* __restrict__ deg, int n) {
  int gtid = blockIdx.x * 256 + threadIdx.x;
  int node = gtid >> 3, l = gtid & 7;
  if (node >= n) return;
  int kend = min(cnt[node], CAP);
  float v = 0.f;
  for (int k = l; k < kend; k += 8) v += __int_as_float(csrp[(long)node * CAP + k].y);
  v += __shfl_xor(v, 1);
  v += __shfl_xor(v, 2);
  v += __shfl_xor(v, 4);
  if (l == 0) deg[node] = v;
}

__global__ __launch_bounds__(256) void k_ovf_deg(
    const int4* __restrict__ ovf, const int* __restrict__ ovf_cnt,
    float* __restrict__ deg) {
  int m = min(*ovf_cnt, OVF_CAP);
  for (int i = blockIdx.x * 256 + threadIdx.x; i < m; i += gridDim.x * 256)
    atomicAdd(&deg[ovf[i].x], __int_as_float(ovf[i].z));
}

// ---- dinv = 1/sqrt(deg_edges + 1 self-loop) -------------------------------
__global__ __launch_bounds__(256) void k_dinv(
    const float* __restrict__ deg, float* __restrict__ dinv, int n) {
  int i = blockIdx.x * 256 + threadIdx.x;
  if (i < n) dinv[i] = 1.0f / sqrtf(deg[i] + 1.0f);
}

// ---- h1pre = x @ W1  (N x 512 @ 512 x 16) ---------------------------------
// 4 lanes per row-pair; lane q owns float4 indices {q, q+4, ...} so each
// instruction reads 64B-contiguous per row. W1 transposed in LDS:
// W1t[j][k] -> ds_read_b128 at 16B lane stride (conflict-free).
__global__ __launch_bounds__(256) void k_xw1(
    const float* __restrict__ x, const float* __restrict__ W1,
    float* __restrict__ h1pre, int n) {
  __shared__ float W1t[16 * 512];
  {
#pragma unroll
    for (int i = 0; i < 32; ++i) {
      int idx = threadIdx.x + i * 256;     // source flat index = k*16 + j
      int k = idx >> 4, j = idx & 15;
      W1t[j * 512 + k] = W1[idx];
    }
  }
  __syncthreads();
  int gtid = blockIdx.x * 256 + threadIdx.x;
  int rp = gtid >> 2, q = gtid & 3;
  int r0 = rp * 2;
  if (r0 >= n) return;
  int r1 = r0 + 1;
  bool has1 = (r1 < n);
  const float4* x4 = (const float4*)x;
  const float4* W1t4 = (const float4*)W1t;
  float acc0[16], acc1[16];
#pragma unroll
  for (int j = 0; j < 16; ++j) { acc0[j] = 0.f; acc1[j] = 0.f; }
  long rb0 = (long)r0 * 128 + q;
  long rb1 = (long)r1 * 128 + q;
  for (int m = 0; m < 32; ++m) {
    float4 a = x4[rb0 + m * 4];
    float4 b = has1 ? x4[rb1 + m * 4] : make_float4(0.f, 0.f, 0.f, 0.f);
    int p = q + m * 4;                     // float4 index within row
#pragma unroll
    for (int j = 0; j < 16; ++j) {
      float4 w = W1t4[j * 128 + p];        // W1[4p..4p+3][j]
      acc0[j] = fmaf(a.x, w.x, acc0[j]);
      acc0[j] = fmaf(a.y, w.y, acc0[j]);
      acc0[j] = fmaf(a.z, w.z, acc0[j]);
      acc0[j] = fmaf(a.w, w.w, acc0[j]);
      acc1[j] = fmaf(b.x, w.x, acc1[j]);
      acc1[j] = fmaf(b.y, w.y, acc1[j]);
      acc1[j] = fmaf(b.z, w.z, acc1[j]);
      acc1[j] = fmaf(b.w, w.w, acc1[j]);
    }
  }
  // reduce across the 4 k-quarter lanes (quads are wave-aligned)
#pragma unroll
  for (int j = 0; j < 16; ++j) {
    acc0[j] += __shfl_xor(acc0[j], 1);
    acc0[j] += __shfl_xor(acc0[j], 2);
    acc1[j] += __shfl_xor(acc1[j], 1);
    acc1[j] += __shfl_xor(acc1[j], 2);
  }
  if (q == 0) {
    float4* o4 = (float4*)h1pre;
#pragma unroll
    for (int j4 = 0; j4 < 4; ++j4) {
      o4[(long)r0 * 4 + j4] =
          make_float4(acc0[4 * j4], acc0[4 * j4 + 1], acc0[4 * j4 + 2], acc0[4 * j4 + 3]);
      if (has1)
        o4[(long)r1 * 4 + j4] =
            make_float4(acc1[4 * j4], acc1[4 * j4 + 1], acc1[4 * j4 + 2], acc1[4 * j4 + 3]);
    }
  }
}

// ---- gather-aggregate (raw): out[i][j] = dv*(dv*hin[i][j] + Σ w*dinv[s]*hin[s][j])
__global__ __launch_bounds__(256) void k_agg(
    const float* __restrict__ hin, const int2* __restrict__ csrp,
    const int* __restrict__ cnt, const float* __restrict__ dinv,
    float* __restrict__ out, int n) {
  int gtid = blockIdx.x * 256 + threadIdx.x;
  int node = gtid >> 4, j = gtid & 15;
  if (node >= n) return;
  float dv = dinv[node];
  float acc = dv * hin[(long)node * 16 + j];
  int kend = min(cnt[node], CAP);
  const int2* row = csrp + (long)node * CAP;
  for (int k = 0; k < kend; ++k) {
    int2 en = row[k];
    float f = __int_as_float(en.y) * dinv[en.x];
    acc = fmaf(f, hin[(long)en.x * 16 + j], acc);
  }
  out[(long)node * 16 + j] = dv * acc;
}

// ---- overflow-edge aggregate (rare path, normally 0 edges) ----------------
__global__ __launch_bounds__(256) void k_ovf_agg(
    const int4* __restrict__ ovf, const int* __restrict__ ovf_cnt,
    const float* __restrict__ dinv, const float* __restrict__ hin,
    float* __restrict__ out) {
  int m = min(*ovf_cnt, OVF_CAP);
  for (int t = blockIdx.x * 256 + threadIdx.x; t < m * 16; t += gridDim.x * 256) {
    int i = t >> 4, j = t & 15;
    int4 e = ovf[i];
    float f = dinv[e.x] * dinv[e.y] * __int_as_float(e.z);
    atomicAdd(&out[(long)e.x * 16 + j], f * hin[(long)e.y * 16 + j]);
  }
}

// ---- layer-1 epilogue: bias + relu ----------------------------------------
__global__ __launch_bounds__(256) void k_bias_relu(
    float* __restrict__ h, const float* __restrict__ b, int n) {
  int t = blockIdx.x * 256 + threadIdx.x;
  if (t < n * 16) h[t] = fmaxf(h[t] + b[t & 15], 0.0f);
}

// ---- out = agg2 @ W2 + b2  (N x 16 @ 16 x 64) -----------------------------
__global__ __launch_bounds__(256) void k_out(
    const float* __restrict__ agg2, const float* __restrict__ W2,
    const float* __restrict__ b2, float* __restrict__ out, int n) {
  __shared__ float W2s[16 * 64];
#pragma unroll
  for (int s = 0; s < 4; ++s) W2s[threadIdx.x + s * 256] = W2[threadIdx.x + s * 256];
  __syncthreads();
  int gtid = blockIdx.x * 256 + threadIdx.x;
  int i = gtid >> 6, o = gtid & 63;
  if (i >= n) return;
  float acc = b2[o];
#pragma unroll
  for (int j = 0; j < 16; ++j)
    acc = fmaf(agg2[(long)i * 16 + j], W2s[j * 64 + o], acc);
  out[(long)i * 64 + o] = acc;
}

extern "C" void kernel_launch(void* const* d_in, const int* in_sizes, int n_in,
                              void* d_out, int out_size, void* d_ws, size_t ws_size,
                              hipStream_t stream) {
  const float* x  = (const float*)d_in[0];
  const int*   ei = (const int*)d_in[1];
  const float* ew = (const float*)d_in[2];
  const float* W1 = (const float*)d_in[3];
  const float* b1 = (const float*)d_in[4];
  const float* W2 = (const float*)d_in[5];
  const float* b2 = (const float*)d_in[6];
  float* out = (float*)d_out;
  int n  = in_sizes[0] / 512;
  int ne = in_sizes[1] / 2;

  char* ws = (char*)d_ws;
  size_t off = 0;
  auto alloc = [&](size_t bytes) {
    size_t r = off;
    off += (bytes + 255) & ~(size_t)255;
    return r;
  };
  int*   cnt     = (int*)  (ws + alloc((size_t)n * 4));
  int*   ovf_cnt = (int*)  (ws + alloc(4));
  size_t zero_span = off;                       // [0, zero_span) zeroed per call
  float* deg     = (float*)(ws + alloc((size_t)n * 4));
  float* dinv    = (float*)(ws + alloc((size_t)n * 4));
  float* h1pre   = (float*)(ws + alloc((size_t)n * 16 * 4));
  float* h1      = (float*)(ws + alloc((size_t)n * 16 * 4));
  float* agg2    = (float*)(ws + alloc((size_t)n * 16 * 4));
  int2*  csrp    = (int2*) (ws + alloc((size_t)n * CAP * 8));
  int4*  ovf     = (int4*) (ws + alloc((size_t)OVF_CAP * 16));
  (void)ws_size; (void)n_in; (void)out_size;

  hipMemsetAsync(d_ws, 0, zero_span, stream);

  int gE = (ne + 255) / 256;
  k_fill_pad<<<gE, 256, 0, stream>>>(ei, ew, cnt, csrp, ovf, ovf_cnt, ne);

  k_deg<<<(n * 8 + 255) / 256, 256, 0, stream>>>(csrp, cnt, deg, n);
  k_ovf_deg<<<16, 256, 0, stream>>>(ovf, ovf_cnt, deg);
  k_dinv<<<(n + 255) / 256, 256, 0, stream>>>(deg, dinv, n);

  int nrp = (n + 1) / 2;
  k_xw1<<<(nrp * 4 + 255) / 256, 256, 0, stream>>>(x, W1, h1pre, n);

  int gN16 = (n * 16 + 255) / 256;
  k_agg<<<gN16, 256, 0, stream>>>(h1pre, csrp, cnt, dinv, h1, n);
  k_ovf_agg<<<64, 256, 0, stream>>>(ovf, ovf_cnt, dinv, h1pre, h1);
  k_bias_relu<<<gN16, 256, 0, stream>>>(h1, b1, n);

  k_agg<<<gN16, 256, 0, stream>>>(h1, csrp, cnt, dinv, agg2, n);
  k_ovf_agg<<<64, 256, 0, stream>>>(ovf, ovf_cnt, dinv, h1, agg2);

  k_out<<<(n * 64 + 255) / 256, 256, 0, stream>>>(agg2, W2, b2, out, n);
}